// Round 6
// baseline (204.919 us; speedup 1.0000x reference)
//
#include <hip/hip_runtime.h>

#define BTOT    524288
#define TN      6              // Taylor order for expm (norm<=0.5 -> rem ~1.5e-6)

typedef __attribute__((ext_vector_type(8))) short s8v;   // 8 x bf16 bits
typedef __attribute__((ext_vector_type(4))) short s4v;   // 4 x bf16 bits
typedef __attribute__((ext_vector_type(4))) float f4v;

#define MFMA(a,b,c) __builtin_amdgcn_mfma_f32_16x16x32_bf16((a),(b),(c),0,0,0)
#define KEEP(x) asm volatile("" : "+v"(x))
#define BC(x) __builtin_bit_cast(s8v, x)

__device__ __forceinline__ short f2b(float f) {          // f32 -> bf16 (RNE)
  union { float f; unsigned u; } v; v.f = f;
  unsigned r = v.u + 0x7fffu + ((v.u >> 16) & 1u);
  return (short)(r >> 16);
}
__device__ __forceinline__ float b2f(short s) {
  union { float f; unsigned u; } v; v.u = ((unsigned)(unsigned short)s) << 16;
  return v.f;
}
__device__ __forceinline__ s8v pack8(f4v u, f4v v) {
  s8v w;
  w[0] = f2b(u[0]); w[1] = f2b(u[1]); w[2] = f2b(u[2]); w[3] = f2b(u[3]);
  w[4] = f2b(v[0]); w[5] = f2b(v[1]); w[6] = f2b(v[2]); w[7] = f2b(v[3]);
  return w;
}
__device__ __forceinline__ s4v pack4(f4v a) {
  s4v w; w[0]=f2b(a[0]); w[1]=f2b(a[1]); w[2]=f2b(a[2]); w[3]=f2b(a[3]); return w;
}
__device__ __forceinline__ s4v pack4r(f4v a) {
  s4v w;
  w[0]=f2b(fmaxf(a[0],0.f)); w[1]=f2b(fmaxf(a[1],0.f));
  w[2]=f2b(fmaxf(a[2],0.f)); w[3]=f2b(fmaxf(a[3],0.f));
  return w;
}

// MFMA fragment load from a padded row-major LDS tile (prep kernel only)
__device__ __forceinline__ s8v ldfrag(const short* base, int row0, int kbase, int stride) {
  const int l = threadIdx.x & 63;
  return *(const s8v*)(base + (row0 + (l & 15)) * stride + kbase + (l >> 4) * 8);
}
// frag-linear chunk read: lane-linear 16B -> conflict-free
__device__ __forceinline__ s8v ldw(const short* base, int chunk) {
  return *(const s8v*)(base + (chunk * 64 + (threadIdx.x & 63)) * 8);
}

// ---- ws layout (shorts): fragment-linear packed weights ----
#define WS_M1   0
#define WS_I1   8192
#define WS_W1   20480
#define WS_W2K  26624
#define WS_I2   38912

__device__ __forceinline__ int fragidx(int n, int k, int KS) {
  int jj = n >> 4, ks = k >> 5;
  int l = (n & 15) | (((k >> 3) & 3) << 4);
  return ((jj * KS + ks) * 64 + l) * 8 + (k & 7);
}

// ---------------------------------------------------------------------------
// Kernel 1: expm(A*t/24) via scaling+squaring Taylor (split-bf16 MFMA), then
// emit ALL weights as bf16 fragment-linear buffers in ws. Serial reductions
// replaced with wave-parallel shuffle reductions.
// ---------------------------------------------------------------------------
__global__ __launch_bounds__(512, 2) void koop_prep(
    const float* __restrict__ tptr, const float* __restrict__ Ag,
    const float* __restrict__ W2g, const float* __restrict__ w1g,
    const float* __restrict__ i1g, const float* __restrict__ i2g,
    short* __restrict__ wsp) {
  extern __shared__ __align__(16) char smem[];
  short* RThi = (short*)smem;              // [128][136]
  short* RTlo = RThi + 128 * 136;          // [128][136]
  float* sW2  = (float*)(RTlo + 128 * 136);// [128][96]
  float* sred = sW2 + 128 * 96;            // [130]
  float* scratch = (float*)smem;           // [128][128] alias (dead before RT writes)

  const int tid = threadIdx.x;
  const int lane = tid & 63, wid = tid >> 6;
  const int c_ = lane & 15, g_ = lane >> 4;
  const int mr = wid * 16;

  for (int e = tid; e < 6144; e += 512)
    wsp[WS_W1 + fragidx(e >> 6, e & 63, 2)] = f2b(w1g[e]);
  for (int e = tid; e < 12288; e += 512)
    wsp[WS_I1 + fragidx(e >> 7, e & 127, 4)] = f2b(i1g[e]);
  for (int e = tid; e < 6144; e += 512)
    wsp[WS_I2 + fragidx(e / 96, e % 96, 3)] = f2b(i2g[e]);

  const float s = tptr[0] * (1.0f / 24.0f);
  for (int i = tid; i < 128 * 128; i += 512) scratch[i] = Ag[i] * s;
  for (int i = tid; i < 128 * 96;  i += 512) sW2[i] = W2g[i];
  __syncthreads();

  {  // inf-norm: 4 threads/row, shuffle-reduce
    const int row = tid >> 2, q = tid & 3;
    float su = 0.f;
    const float* rp = scratch + row * 128 + q * 32;
#pragma unroll 8
    for (int j = 0; j < 32; ++j) su += fabsf(rp[j]);
    su += __shfl_xor(su, 1);
    su += __shfl_xor(su, 2);
    if (q == 0) sred[row] = su;
  }
  __syncthreads();
  if (tid < 64) {
    float m = fmaxf(sred[tid], sred[tid + 64]);
#pragma unroll
    for (int d = 32; d; d >>= 1) m = fmaxf(m, __shfl_xor(m, d));
    if (tid == 0) {
      int j = 0;
      if (m > 0.5f) {
        j = (int)ceilf(log2f(m * 2.0f));
        if (j < 0) j = 0; if (j > 20) j = 20;
      }
      sred[128] = (float)j; sred[129] = exp2f(-(float)j);
    }
  }
  __syncthreads();
  const int jsq = (int)sred[128];
  const float sc = sred[129];

  s8v Ahi[4], Alo[4];
#pragma unroll
  for (int ks = 0; ks < 4; ++ks) {
    const float* p = scratch + (mr + c_) * 128 + ks * 32 + g_ * 8;
    f4v u = *(const f4v*)p, v = *(const f4v*)(p + 4);
    float vals[8] = {u[0], u[1], u[2], u[3], v[0], v[1], v[2], v[3]};
#pragma unroll
    for (int i = 0; i < 8; ++i) {
      float y = vals[i] * sc;
      short h = f2b(y);
      Ahi[ks][i] = h;
      Alo[ks][i] = f2b(y - b2f(h));
    }
  }
  float yv[32];
#pragma unroll
  for (int e = 0; e < 32; ++e) yv[e] = scratch[tid * 32 + e];
  __syncthreads();

#pragma unroll
  for (int e = 0; e < 32; ++e) {
    int idx = tid * 32 + e;
    int r = idx >> 7, c = idx & 127;
    float v = yv[e] * sc * (1.0f / TN) + ((r == c) ? 1.0f : 0.0f);
    short h = f2b(v);
    RThi[c * 136 + r] = h;
    RTlo[c * 136 + r] = f2b(v - b2f(h));
  }
  __syncthreads();

  for (int k = TN - 1; k >= 1; --k) {
    f4v acc[8];
#pragma unroll
    for (int nt = 0; nt < 8; ++nt) acc[nt] = (f4v){0.f, 0.f, 0.f, 0.f};
#pragma unroll
    for (int ks = 0; ks < 4; ++ks) {
#pragma unroll
      for (int nt = 0; nt < 8; ++nt) {
        s8v bh = ldfrag(RThi, nt * 16, ks * 32, 136);
        s8v bl = ldfrag(RTlo, nt * 16, ks * 32, 136);
        acc[nt] = MFMA(Ahi[ks], bh, acc[nt]);
        acc[nt] = MFMA(Alo[ks], bh, acc[nt]);
        acc[nt] = MFMA(Ahi[ks], bl, acc[nt]);
      }
    }
    __syncthreads();
    const float invk = 1.0f / (float)k;
#pragma unroll
    for (int nt = 0; nt < 8; ++nt)
#pragma unroll
      for (int r = 0; r < 4; ++r) {
        int row = mr + g_ * 4 + r, col = nt * 16 + c_;
        float v = acc[nt][r] * invk + ((row == col) ? 1.0f : 0.0f);
        short h = f2b(v);
        RThi[col * 136 + row] = h;
        RTlo[col * 136 + row] = f2b(v - b2f(h));
      }
    __syncthreads();
  }

  for (int it = 0; it < jsq; ++it) {
    s8v Shi[4], Slo[4];
#pragma unroll
    for (int ks = 0; ks < 4; ++ks) {
      int m = mr + c_;
      int k0 = ks * 32 + g_ * 8;
#pragma unroll
      for (int i = 0; i < 8; ++i) {
        Shi[ks][i] = RThi[(k0 + i) * 136 + m];
        Slo[ks][i] = RTlo[(k0 + i) * 136 + m];
      }
    }
    f4v acc[8];
#pragma unroll
    for (int nt = 0; nt < 8; ++nt) acc[nt] = (f4v){0.f, 0.f, 0.f, 0.f};
#pragma unroll
    for (int ks = 0; ks < 4; ++ks) {
#pragma unroll
      for (int nt = 0; nt < 8; ++nt) {
        s8v bh = ldfrag(RThi, nt * 16, ks * 32, 136);
        s8v bl = ldfrag(RTlo, nt * 16, ks * 32, 136);
        acc[nt] = MFMA(Shi[ks], bh, acc[nt]);
        acc[nt] = MFMA(Slo[ks], bh, acc[nt]);
        acc[nt] = MFMA(Shi[ks], bl, acc[nt]);
      }
    }
    __syncthreads();
#pragma unroll
    for (int nt = 0; nt < 8; ++nt)
#pragma unroll
      for (int r = 0; r < 4; ++r) {
        int row = mr + g_ * 4 + r, col = nt * 16 + c_;
        float v = acc[nt][r];
        short h = f2b(v);
        RThi[col * 136 + row] = h;
        RTlo[col * 136 + row] = f2b(v - b2f(h));
      }
    __syncthreads();
  }

  for (int e = tid; e < 128 * 64; e += 512) {
    int n = e >> 6, kk = e & 63;
    float v = b2f(RThi[kk * 136 + n]) + b2f(RTlo[kk * 136 + n]);
    wsp[WS_M1 + fragidx(n, kk, 2)] = f2b(v);
  }

  {
    s8v Shi[4], Slo[4];
#pragma unroll
    for (int ks = 0; ks < 4; ++ks) {
      int m = mr + c_;
      int k0 = ks * 32 + g_ * 8;
#pragma unroll
      for (int i = 0; i < 8; ++i) {
        Shi[ks][i] = RThi[(k0 + i) * 136 + m];
        Slo[ks][i] = RTlo[(k0 + i) * 136 + m];
      }
    }
    f4v acc[6];
#pragma unroll
    for (int nt = 0; nt < 6; ++nt) acc[nt] = (f4v){0.f, 0.f, 0.f, 0.f};
#pragma unroll
    for (int ks = 0; ks < 4; ++ks) {
#pragma unroll
      for (int nt = 0; nt < 6; ++nt) {
        s8v bh, bl;
#pragma unroll
        for (int i = 0; i < 8; ++i) {
          float v = sW2[(ks * 32 + g_ * 8 + i) * 96 + nt * 16 + c_];
          short h = f2b(v);
          bh[i] = h;
          bl[i] = f2b(v - b2f(h));
        }
        acc[nt] = MFMA(Shi[ks], bh, acc[nt]);
        acc[nt] = MFMA(Slo[ks], bh, acc[nt]);
        acc[nt] = MFMA(Shi[ks], bl, acc[nt]);
      }
    }
#pragma unroll
    for (int nt = 0; nt < 6; ++nt)
#pragma unroll
      for (int r = 0; r < 4; ++r)
        wsp[WS_W2K + fragidx(mr + g_ * 4 + r, nt * 16 + c_, 3)] = f2b(acc[nt][r]);
  }
}

// ---------------------------------------------------------------------------
// Kernel 2: BARRIER-FREE per-wave pipeline. 512 thr (8 waves), 1 block/CU.
// Each wave owns a private LDS slice (H 32x192B swz(r&3), Z/H2 32x256B
// swz(r&7)) and runs 32-row microtiles end-to-end with no __syncthreads.
// Shared read-only LDS: M1+I1 frag-linear (40KB) + biases. W1/W2K/I2 pinned
// in VGPRs (192 regs). X: global->reg->pack8 (no LDS staging).
// ---------------------------------------------------------------------------
__global__ __launch_bounds__(512, 1) void koop_main(
    const float* __restrict__ xg, const float* __restrict__ b1g,
    const float* __restrict__ bi1g, const float* __restrict__ bi2g,
    const short* __restrict__ wsp, float* __restrict__ outg) {
  extern __shared__ __align__(16) char smem[];
  short* sWf = (short*)smem;                 // M1f [0,8192sh) + I1f [8192,20480sh)
  float* sB  = (float*)(smem + 40960);       // b1[96] bi1[96] bi2[64]
  char*  actB = smem + 41984 + (threadIdx.x >> 6) * 14336;  // per-wave slice
  // H : [actB, +6144)       stride 192B, swz ((r&3)<<4)  (2-way worst: free)
  // Z : [actB+6144, +8192)  stride 256B, swz ((r&7)<<4)  (conflict-free); H2 reuses

  const int tid = threadIdx.x, lane = tid & 63, wid = tid >> 6;
  const int c_ = lane & 15, g_ = lane >> 4;

  // ---- stage shared weights + biases to LDS ----
  for (int i = tid; i < 2560; i += 512)      // 40960B = 2560 f4v
    ((f4v*)sWf)[i] = ((const f4v*)(wsp + WS_M1))[i];
  if (tid < 96) sB[tid] = b1g[tid];
  else if (tid < 192) sB[tid] = bi1g[tid - 96];
  else if (tid < 256) sB[tid] = bi2g[tid - 192];

  // ---- VGPR weights (pinned): W1 12 + W2K 24 + I2 12 frags = 192 regs ----
  f4v W1v[6][2], W2Kv[8][3], I2v[4][3];
#pragma unroll
  for (int fb = 0; fb < 6; ++fb)
#pragma unroll
    for (int ks = 0; ks < 2; ++ks) {
      W1v[fb][ks] = *(const f4v*)(wsp + WS_W1 + ((fb * 2 + ks) * 64 + lane) * 8);
      KEEP(W1v[fb][ks]);
    }
#pragma unroll
  for (int fb = 0; fb < 8; ++fb)
#pragma unroll
    for (int ks = 0; ks < 3; ++ks) {
      W2Kv[fb][ks] = *(const f4v*)(wsp + WS_W2K + ((fb * 3 + ks) * 64 + lane) * 8);
      KEEP(W2Kv[fb][ks]);
    }
#pragma unroll
  for (int fb = 0; fb < 4; ++fb)
#pragma unroll
    for (int ks = 0; ks < 3; ++ks) {
      I2v[fb][ks] = *(const f4v*)(wsp + WS_I2 + ((fb * 3 + ks) * 64 + lane) * 8);
      KEEP(I2v[fb][ks]);
    }
  __syncthreads();   // the ONLY barrier

  const int wgid = blockIdx.x * 8 + wid;     // 0..2047
  for (int it = 0; it < 8; ++it) {
    const size_t r0 = ((size_t)(it * 2048 + wgid)) * 32;

    // ---- X: global -> regs -> bf16 B-frags ----
    s8v bx[2][2];
#pragma unroll
    for (int bb = 0; bb < 2; ++bb)
#pragma unroll
      for (int ks = 0; ks < 2; ++ks) {
        const float* p = xg + (r0 + bb * 16 + c_) * 64 + ks * 32 + g_ * 8;
        bx[bb][ks] = pack8(*(const f4v*)p, *(const f4v*)(p + 4));
      }

    // ---- stage 1: H = relu(W1 . X^T + b1) ----
#pragma unroll
    for (int fb = 0; fb < 6; ++fb) {
      f4v bias = *(const f4v*)(sB + fb * 16 + g_ * 4);
#pragma unroll
      for (int bb = 0; bb < 2; ++bb) {
        f4v acc = bias;
        acc = MFMA(BC(W1v[fb][0]), bx[bb][0], acc);
        acc = MFMA(BC(W1v[fb][1]), bx[bb][1], acc);
        const int r = bb * 16 + c_;
        *(s4v*)(actB + ((r * 192 + fb * 32 + g_ * 8) ^ ((r & 3) << 4))) = pack4r(acc);
      }
    }

    // ---- stage 2: Z = M1 . X^T + W2K . H^T ----
    s8v hb[2][3];
#pragma unroll
    for (int bb = 0; bb < 2; ++bb) {
      const int r = bb * 16 + c_;
#pragma unroll
      for (int ks = 0; ks < 3; ++ks)
        hb[bb][ks] = *(const s8v*)(actB + ((r * 192 + ks * 64 + g_ * 16) ^ ((r & 3) << 4)));
    }
#pragma unroll
    for (int fb = 0; fb < 8; ++fb) {
      s8v m0 = ldw(sWf, fb * 2 + 0);
      s8v m1 = ldw(sWf, fb * 2 + 1);
#pragma unroll
      for (int bb = 0; bb < 2; ++bb) {
        f4v acc = (f4v){0.f, 0.f, 0.f, 0.f};
        acc = MFMA(m0, bx[bb][0], acc);
        acc = MFMA(m1, bx[bb][1], acc);
        acc = MFMA(BC(W2Kv[fb][0]), hb[bb][0], acc);
        acc = MFMA(BC(W2Kv[fb][1]), hb[bb][1], acc);
        acc = MFMA(BC(W2Kv[fb][2]), hb[bb][2], acc);
        const int r = bb * 16 + c_;
        *(s4v*)(actB + 6144 + ((r * 256 + fb * 32 + g_ * 8) ^ ((r & 7) << 4))) = pack4(acc);
      }
    }

    // ---- stage 3: H2 = relu(I1 . Z^T + bi1), H2 overwrites Z buffer ----
    s8v zb[2][4];
#pragma unroll
    for (int bb = 0; bb < 2; ++bb) {
      const int r = bb * 16 + c_;
#pragma unroll
      for (int ks = 0; ks < 4; ++ks)
        zb[bb][ks] = *(const s8v*)(actB + 6144 + ((r * 256 + ks * 64 + g_ * 16) ^ ((r & 7) << 4)));
    }
#pragma unroll
    for (int fb = 0; fb < 6; ++fb) {
      s8v i0 = ldw(sWf + 8192, fb * 4 + 0);
      s8v i1 = ldw(sWf + 8192, fb * 4 + 1);
      s8v i2 = ldw(sWf + 8192, fb * 4 + 2);
      s8v i3 = ldw(sWf + 8192, fb * 4 + 3);
      f4v bias = *(const f4v*)(sB + 96 + fb * 16 + g_ * 4);
#pragma unroll
      for (int bb = 0; bb < 2; ++bb) {
        f4v acc = bias;
        acc = MFMA(i0, zb[bb][0], acc);
        acc = MFMA(i1, zb[bb][1], acc);
        acc = MFMA(i2, zb[bb][2], acc);
        acc = MFMA(i3, zb[bb][3], acc);
        const int r = bb * 16 + c_;
        *(s4v*)(actB + 6144 + ((r * 256 + fb * 32 + g_ * 8) ^ ((r & 7) << 4))) = pack4r(acc);
      }
    }

    // ---- stage 4: OUT = I2 . H2^T + bi2 -> global ----
    s8v h2[2][3];
#pragma unroll
    for (int bb = 0; bb < 2; ++bb) {
      const int r = bb * 16 + c_;
#pragma unroll
      for (int ks = 0; ks < 3; ++ks)
        h2[bb][ks] = *(const s8v*)(actB + 6144 + ((r * 256 + ks * 64 + g_ * 16) ^ ((r & 7) << 4)));
    }
#pragma unroll
    for (int fb = 0; fb < 4; ++fb) {
      f4v bias = *(const f4v*)(sB + 192 + fb * 16 + g_ * 4);
#pragma unroll
      for (int bb = 0; bb < 2; ++bb) {
        f4v acc = bias;
        acc = MFMA(BC(I2v[fb][0]), h2[bb][0], acc);
        acc = MFMA(BC(I2v[fb][1]), h2[bb][1], acc);
        acc = MFMA(BC(I2v[fb][2]), h2[bb][2], acc);
        *(f4v*)(outg + (r0 + bb * 16 + c_) * 64 + fb * 16 + g_ * 4) = acc;
      }
    }
  }
}

#define PREP_LDS (128 * 136 * 2 * 2 + 128 * 96 * 4 + 130 * 4)   // 119304 B
#define MAIN_LDS (41984 + 8 * 14336)                             // 156672 B

extern "C" void kernel_launch(void* const* d_in, const int* in_sizes, int n_in,
                              void* d_out, int out_size, void* d_ws, size_t ws_size,
                              hipStream_t stream) {
  (void)in_sizes; (void)n_in; (void)out_size; (void)ws_size;
  const float* t     = (const float*)d_in[0];
  const float* x     = (const float*)d_in[1];
  const float* A     = (const float*)d_in[2];
  const float* phiW1 = (const float*)d_in[3];
  const float* phib1 = (const float*)d_in[4];
  const float* phiW2 = (const float*)d_in[5];
  const float* invW1 = (const float*)d_in[6];
  const float* invb1 = (const float*)d_in[7];
  const float* invW2 = (const float*)d_in[8];
  const float* invb2 = (const float*)d_in[9];
  float* out = (float*)d_out;
  short* wsp = (short*)d_ws;

  (void)hipFuncSetAttribute((const void*)koop_prep,
                            hipFuncAttributeMaxDynamicSharedMemorySize, PREP_LDS);
  (void)hipFuncSetAttribute((const void*)koop_main,
                            hipFuncAttributeMaxDynamicSharedMemorySize, MAIN_LDS);

  koop_prep<<<1, 512, PREP_LDS, stream>>>(t, A, phiW2, phiW1, invW1, invW2, wsp);
  koop_main<<<256, 512, MAIN_LDS, stream>>>(x, phib1, invb1, invb2, wsp, out);
}